// Round 2
// baseline (2555.379 us; speedup 1.0000x reference)
//
#include <hip/hip_runtime.h>
#include <stdint.h>

#define T_TOK 4096
#define HDIM  2048
#define NEXP  32
#define IDIM  1024
#define TOPK  8
#define BM    128
#define BK    32
#define MAXT  320
#define BSTR  40            // LDS row/col stride in elems (80B: 16B-aligned, 2-way banks on b128)
#define SUBSZ (16 * BSTR)   // elems per B subtile [16 n][32 k]+pad

typedef __attribute__((ext_vector_type(2))) float  f32x2;
typedef __attribute__((ext_vector_type(4))) float  f32x4;
typedef __attribute__((ext_vector_type(8))) short  s16x8;

// ---- workspace layout (32-bit word offsets) ----
#define WS_COUNTS  0
#define WS_OFFSETS 64
#define WS_CURSORS 128
#define WS_TILE_E  256
#define WS_TILE_R  576
#define WS_TILE_V  896
#define WS_EXPSLOT 1216
#define WS_WSLOT   33984
#define WS_TOKROW  66752
#define WS_WROW    99520
#define HBUF_BYTE  532480ull   // 4KB-aligned; Hbuf = 32768 x 1024 bf16 = 64 MiB

__device__ __forceinline__ uint32_t pack_trunc(float a, float b) {
  // two fp32 -> packed bf16 pair (truncation; systematic bias ~0.2%, fine vs 0.62 tol)
  return (__float_as_uint(a) >> 16) | (__float_as_uint(b) & 0xffff0000u);
}
__device__ __forceinline__ uint16_t f2bf_rne(float f) {
  uint32_t u = __float_as_uint(f);
  u += 0x7fffu + ((u >> 16) & 1u);
  return (uint16_t)(u >> 16);
}

// ---------------- router: logits -> softmax -> top8 -> renorm ----------------
__global__ __launch_bounds__(256) void k_router(
    const float* __restrict__ hs, const float* __restrict__ gw,
    float* __restrict__ out_ids, int* __restrict__ wsi, float* __restrict__ wsf) {
  const int t = blockIdx.x;
  const int tid = threadIdx.x;
  const int e = tid & 31, seg = tid >> 5;
  const float* hrow = hs + (size_t)t * HDIM;
  const int h0 = seg * 256;
  float acc = 0.f;
  for (int h = h0; h < h0 + 256; ++h)
    acc += hrow[h] * gw[h * NEXP + e];
  __shared__ float part[8][32];
  __shared__ float logit[32];
  part[seg][e] = acc;
  __syncthreads();
  if (tid < 32) {
    float s = 0.f;
#pragma unroll
    for (int j = 0; j < 8; ++j) s += part[j][tid];
    logit[tid] = s;
  }
  __syncthreads();
  if (tid == 0) {
    float l[32];
    float mx = -1e30f;
    for (int i = 0; i < 32; ++i) { l[i] = logit[i]; mx = fmaxf(mx, l[i]); }
    int ids[8]; float wv[8];
    float wsum = 0.f;
    for (int k = 0; k < 8; ++k) {
      int best = 0; float bv = -1e30f;
      for (int i = 0; i < 32; ++i)
        if (l[i] > bv) { bv = l[i]; best = i; }   // strict > : ties -> lowest idx (lax.top_k)
      ids[k] = best;
      float w = __expf(bv - mx);                  // softmax denom cancels in renorm
      wv[k] = w; wsum += w;
      l[best] = -1e30f;
    }
    float inv = 1.f / wsum;
    for (int k = 0; k < 8; ++k) {
      int slot = t * TOPK + k;
      out_ids[slot] = (float)ids[k];
      wsi[WS_EXPSLOT + slot] = ids[k];
      wsf[WS_WSLOT + slot] = wv[k] * inv;
      atomicAdd(&wsi[WS_COUNTS + ids[k]], 1);
    }
  }
}

// ---------------- setup: prefix sums + tile table ----------------
__global__ void k_setup(int* __restrict__ wsi) {
  if (threadIdx.x != 0 || blockIdx.x != 0) return;
  int off = 0;
  for (int e = 0; e < NEXP; ++e) {
    wsi[WS_OFFSETS + e] = off;
    off += wsi[WS_COUNTS + e];
    wsi[WS_CURSORS + e] = 0;
  }
  wsi[WS_OFFSETS + NEXP] = off;
  int nt = 0;
  for (int e = 0; e < NEXP; ++e) {
    int c = wsi[WS_COUNTS + e];
    int r0 = wsi[WS_OFFSETS + e];
    for (int j = 0; j < c; j += BM) {
      wsi[WS_TILE_E + nt] = e;
      wsi[WS_TILE_R + nt] = r0 + j;
      wsi[WS_TILE_V + nt] = (c - j < BM) ? (c - j) : BM;
      ++nt;
    }
  }
  for (; nt < MAXT; ++nt) wsi[WS_TILE_E + nt] = -1;
}

// ---------------- scatter: slot -> row (expert-major) ----------------
__global__ __launch_bounds__(256) void k_scatter(int* __restrict__ wsi, float* __restrict__ wsf) {
  int s = blockIdx.x * 256 + threadIdx.x;
  int e = wsi[WS_EXPSLOT + s];
  float w = wsf[WS_WSLOT + s];
  int pos = atomicAdd(&wsi[WS_CURSORS + e], 1);
  int r = wsi[WS_OFFSETS + e] + pos;
  wsi[WS_TOKROW + r] = s >> 3;
  wsf[WS_WROW + r] = w;
}

// ---------------- GEMM1: X[gathered] @ [Wg|Wu] -> silu(g)*u -> Hbuf ----------------
// block tile: 128 rows x 64 i-cols (gate AND up). B staged COLUMN-major in LDS:
// 8 subtiles [16 n][32 k], sub(v) for virtual col v in [0,128):
//   v<64: gate i_off=v; v>=64: up i_off=v-64; sub = ((v>>5)&1)*4 + ((v>>4)&1) + (v>=64 ? 2 : 0)
// Fragment read: wave wc reads subtiles wc*4+n -> one b128 per operand (no tr_read, no asm).
__global__ __launch_bounds__(256) void k_gemm1(
    const float* __restrict__ hs, const float* __restrict__ wgw, const float* __restrict__ wuw,
    const int* __restrict__ wsi, uint16_t* __restrict__ hbuf) {
  const int tile = blockIdx.x;
  const int e = wsi[WS_TILE_E + tile];
  if (e < 0) return;
  const int row0  = wsi[WS_TILE_R + tile];
  const int vrows = wsi[WS_TILE_V + tile];
  const int i0 = blockIdx.y * 64;

  __shared__ uint16_t As[BM * BSTR];   // [128 m][32 k]+pad, row-major
  __shared__ uint16_t Bt[8 * SUBSZ];   // 8 subtiles, col-major [16 n][32 k]+pad

  const int tid = threadIdx.x;

  // A: 2 threads per row, 16 fp32 each
  const int ar = tid >> 1, ah = tid & 1;
  const int arow = row0 + (ar < vrows ? ar : vrows - 1);  // clamp padded rows (masked in epilogue)
  const int tok = wsi[WS_TOKROW + arow];
  const float* aptr = hs + (size_t)tok * HDIM + ah * 16;

  // B: thread t handles virtual cols v=2p, v+1 (p=t&63), k = kb..kb+7 (kb=(t>>6)*8)
  const int p  = tid & 63;
  const int kb = (tid >> 6) * 8;
  const int v  = 2 * p;
  const int vup = (v >= 64) ? 1 : 0;
  const float* bptr = (vup ? wuw : wgw) + (size_t)e * (size_t)HDIM * IDIM
                    + (size_t)kb * IDIM + i0 + (v & 63);
  const int sub  = ((v >> 5) & 1) * 4 + ((v >> 4) & 1) + vup * 2;
  uint16_t* bw0 = &Bt[sub * SUBSZ + (v & 15) * BSTR + kb];

  f32x4 apf[4]; f32x2 bpf[8];
#pragma unroll
  for (int q = 0; q < 4; ++q) apf[q] = ((const f32x4*)aptr)[q];
#pragma unroll
  for (int j = 0; j < 8; ++j) bpf[j] = *(const f32x2*)(bptr + (size_t)j * IDIM);

  const int lane = tid & 63;
  const int wv = tid >> 6, wr = wv >> 1, wc = wv & 1;
  const int arf = wr * 64 + (lane & 15);
  const int kg  = (lane >> 4) * 8;

  f32x4 acc[4][4];
#pragma unroll
  for (int m = 0; m < 4; ++m)
#pragma unroll
    for (int n = 0; n < 4; ++n)
      acc[m][n] = (f32x4){0.f, 0.f, 0.f, 0.f};

  const int asw = ar * BSTR + ah * 16;

  for (int kt = 0; kt < HDIM / BK; ++kt) {
    uint4 w0, w1;
    w0.x = pack_trunc(apf[0][0], apf[0][1]); w0.y = pack_trunc(apf[0][2], apf[0][3]);
    w0.z = pack_trunc(apf[1][0], apf[1][1]); w0.w = pack_trunc(apf[1][2], apf[1][3]);
    w1.x = pack_trunc(apf[2][0], apf[2][1]); w1.y = pack_trunc(apf[2][2], apf[2][3]);
    w1.z = pack_trunc(apf[3][0], apf[3][1]); w1.w = pack_trunc(apf[3][2], apf[3][3]);
    *(uint4*)(&As[asw])     = w0;
    *(uint4*)(&As[asw + 8]) = w1;
    uint4 c0, c1;
    c0.x = pack_trunc(bpf[0][0], bpf[1][0]); c0.y = pack_trunc(bpf[2][0], bpf[3][0]);
    c0.z = pack_trunc(bpf[4][0], bpf[5][0]); c0.w = pack_trunc(bpf[6][0], bpf[7][0]);
    c1.x = pack_trunc(bpf[0][1], bpf[1][1]); c1.y = pack_trunc(bpf[2][1], bpf[3][1]);
    c1.z = pack_trunc(bpf[4][1], bpf[5][1]); c1.w = pack_trunc(bpf[6][1], bpf[7][1]);
    *(uint4*)(bw0)        = c0;    // col v,   k kb..kb+7
    *(uint4*)(bw0 + BSTR) = c1;    // col v+1
    __syncthreads();
    if (kt + 1 < HDIM / BK) {
      const f32x4* pa = (const f32x4*)(aptr + (kt + 1) * BK);
#pragma unroll
      for (int q = 0; q < 4; ++q) apf[q] = pa[q];
      const float* pb = bptr + (size_t)(kt + 1) * BK * IDIM;
#pragma unroll
      for (int j = 0; j < 8; ++j) bpf[j] = *(const f32x2*)(pb + (size_t)j * IDIM);
    }
    s16x8 af[4];
#pragma unroll
    for (int m = 0; m < 4; ++m)
      af[m] = *(const s16x8*)(&As[(arf + m * 16) * BSTR + kg]);
    s16x8 bf[4];
#pragma unroll
    for (int n = 0; n < 4; ++n)
      bf[n] = *(const s16x8*)(&Bt[(wc * 4 + n) * SUBSZ + (lane & 15) * BSTR + kg]);
#pragma unroll
    for (int m = 0; m < 4; ++m)
#pragma unroll
      for (int n = 0; n < 4; ++n)
        acc[m][n] = __builtin_amdgcn_mfma_f32_16x16x32_bf16(af[m], bf[n], acc[m][n], 0, 0, 0);
    __syncthreads();
  }

  const int rb = (lane >> 4) << 2;
  const int cb = lane & 15;
#pragma unroll
  for (int m = 0; m < 4; ++m) {
#pragma unroll
    for (int r = 0; r < 4; ++r) {
      const int rl = wr * 64 + m * 16 + rb + r;
      if (rl < vrows) {
        uint16_t* hrow2 = hbuf + (size_t)(row0 + rl) * IDIM;
#pragma unroll
        for (int n = 0; n < 2; ++n) {
          float g = acc[m][n][r];
          float u = acc[m][n + 2][r];
          float hv = g / (1.f + __expf(-g)) * u;
          hrow2[i0 + ((wc * 2 + n) << 4) + cb] = f2bf_rne(hv);
        }
      }
    }
  }
}

// ---------------- GEMM2: Hbuf @ Wd, scaled atomic scatter-add to out ----------------
__global__ __launch_bounds__(256) void k_gemm2(
    const uint16_t* __restrict__ hbuf, const float* __restrict__ wdw,
    const int* __restrict__ wsi, const float* __restrict__ wsf,
    float* __restrict__ out) {
  const int tile = blockIdx.x;
  const int e = wsi[WS_TILE_E + tile];
  if (e < 0) return;
  const int row0  = wsi[WS_TILE_R + tile];
  const int vrows = wsi[WS_TILE_V + tile];
  const int n0 = blockIdx.y * 128;

  __shared__ uint16_t As[BM * BSTR];
  __shared__ uint16_t Bt[8 * SUBSZ];

  const int tid = threadIdx.x;
  const int ar = tid >> 1, ah = tid & 1;
  int rowa = row0 + ar;
  if (rowa > T_TOK * TOPK - 1) rowa = T_TOK * TOPK - 1;  // OOB guard for last padded tile
  const uint16_t* aptr = hbuf + (size_t)rowa * IDIM + ah * 16;

  const int p  = tid & 63;
  const int kb = (tid >> 6) * 8;
  const int v  = 2 * p;                    // real col within 128-wide n-tile
  const float* bptr = wdw + (size_t)e * (size_t)IDIM * HDIM
                    + (size_t)kb * HDIM + n0 + v;
  const int sub = v >> 4;
  uint16_t* bw0 = &Bt[sub * SUBSZ + (v & 15) * BSTR + kb];

  uint4 apf[2]; f32x2 bpf[8];
  apf[0] = ((const uint4*)aptr)[0];
  apf[1] = ((const uint4*)aptr)[1];
#pragma unroll
  for (int j = 0; j < 8; ++j) bpf[j] = *(const f32x2*)(bptr + (size_t)j * HDIM);

  const int lane = tid & 63;
  const int wv = tid >> 6, wr = wv >> 1, wc = wv & 1;
  const int arf = wr * 64 + (lane & 15);
  const int kg  = (lane >> 4) * 8;

  f32x4 acc[4][4];
#pragma unroll
  for (int m = 0; m < 4; ++m)
#pragma unroll
    for (int n = 0; n < 4; ++n)
      acc[m][n] = (f32x4){0.f, 0.f, 0.f, 0.f};

  const int asw = ar * BSTR + ah * 16;

  for (int kt = 0; kt < IDIM / BK; ++kt) {
    *(uint4*)(&As[asw])     = apf[0];
    *(uint4*)(&As[asw + 8]) = apf[1];
    uint4 c0, c1;
    c0.x = pack_trunc(bpf[0][0], bpf[1][0]); c0.y = pack_trunc(bpf[2][0], bpf[3][0]);
    c0.z = pack_trunc(bpf[4][0], bpf[5][0]); c0.w = pack_trunc(bpf[6][0], bpf[7][0]);
    c1.x = pack_trunc(bpf[0][1], bpf[1][1]); c1.y = pack_trunc(bpf[2][1], bpf[3][1]);
    c1.z = pack_trunc(bpf[4][1], bpf[5][1]); c1.w = pack_trunc(bpf[6][1], bpf[7][1]);
    *(uint4*)(bw0)        = c0;
    *(uint4*)(bw0 + BSTR) = c1;
    __syncthreads();
    if (kt + 1 < IDIM / BK) {
      const uint4* pa = (const uint4*)(aptr + (kt + 1) * BK);
      apf[0] = pa[0]; apf[1] = pa[1];
      const float* pb = bptr + (size_t)(kt + 1) * BK * HDIM;
#pragma unroll
      for (int j = 0; j < 8; ++j) bpf[j] = *(const f32x2*)(pb + (size_t)j * HDIM);
    }
    s16x8 af[4];
#pragma unroll
    for (int m = 0; m < 4; ++m)
      af[m] = *(const s16x8*)(&As[(arf + m * 16) * BSTR + kg]);
    s16x8 bf[4];
#pragma unroll
    for (int n = 0; n < 4; ++n)
      bf[n] = *(const s16x8*)(&Bt[(wc * 4 + n) * SUBSZ + (lane & 15) * BSTR + kg]);
#pragma unroll
    for (int m = 0; m < 4; ++m)
#pragma unroll
      for (int n = 0; n < 4; ++n)
        acc[m][n] = __builtin_amdgcn_mfma_f32_16x16x32_bf16(af[m], bf[n], acc[m][n], 0, 0, 0);
    __syncthreads();
  }

  const int rb = (lane >> 4) << 2;
  const int cb = lane & 15;
#pragma unroll
  for (int m = 0; m < 4; ++m) {
#pragma unroll
    for (int r = 0; r < 4; ++r) {
      const int rl = wr * 64 + m * 16 + rb + r;
      if (rl < vrows) {
        const int row = row0 + rl;
        const int tok = wsi[WS_TOKROW + row];
        const float w = wsf[WS_WROW + row];
        float* orow = out + (size_t)tok * HDIM + n0 + wc * 64 + cb;
#pragma unroll
        for (int n = 0; n < 4; ++n)
          atomicAdd(orow + n * 16, w * acc[m][n][r]);
      }
    }
  }
}

extern "C" void kernel_launch(void* const* d_in, const int* in_sizes, int n_in,
                              void* d_out, int out_size, void* d_ws, size_t ws_size,
                              hipStream_t stream) {
  const float* hs = (const float*)d_in[0];
  const float* gw = (const float*)d_in[1];
  const float* wg = (const float*)d_in[2];
  const float* wu = (const float*)d_in[3];
  const float* wd = (const float*)d_in[4];
  float* out = (float*)d_out;
  int*   wsi = (int*)d_ws;
  float* wsf = (float*)d_ws;
  uint16_t* hbuf = (uint16_t*)((char*)d_ws + HBUF_BYTE);

  hipMemsetAsync(d_ws, 0, 4096, stream);                                   // counts/cursors
  hipMemsetAsync(d_out, 0, (size_t)T_TOK * HDIM * sizeof(float), stream);  // atomic target
  k_router<<<T_TOK, 256, 0, stream>>>(hs, gw, out + (size_t)T_TOK * HDIM, wsi, wsf);
  k_setup<<<1, 64, 0, stream>>>(wsi);
  k_scatter<<<T_TOK * TOPK / 256, 256, 0, stream>>>(wsi, wsf);
  k_gemm1<<<dim3(MAXT, IDIM / 64), 256, 0, stream>>>(hs, wg, wu, wsi, hbuf);
  k_gemm2<<<dim3(MAXT, HDIM / 128), 256, 0, stream>>>(hbuf, wd, wsi, wsf, out);
}